// Round 17
// baseline (187.525 us; speedup 1.0000x reference)
//
#include <hip/hip_runtime.h>
#include <math.h>

#define BB 4
#define LL 4096
#define CC 768
#define KHH 7
#define PADK 3
#define ROWS (BB*LL)      // 16384
#define NKP  (BB*KHH*LL)  // 114688
#define GK   (KHH*CC)     // 5376
#define NT   (GK/64)      // 84
#define NKC  (GK/8)       // 672

typedef unsigned short ushort8 __attribute__((ext_vector_type(8)));
typedef unsigned short ushort4v __attribute__((ext_vector_type(4)));
typedef short short8 __attribute__((ext_vector_type(8)));
typedef float f32x4 __attribute__((ext_vector_type(4)));
typedef unsigned int uint4v __attribute__((ext_vector_type(4)));

__device__ __forceinline__ float bf2f(unsigned short u) {
    return __uint_as_float(((unsigned)u) << 16);
}
__device__ __forceinline__ unsigned short f2bf(float x) {
    unsigned u = __float_as_uint(x);
    return (unsigned short)((u + 0x7FFFu + ((u >> 16) & 1u)) >> 16);
}
__device__ __forceinline__ unsigned cvtpk(float lo, float hi) {
    unsigned r;
    asm("v_cvt_pk_bf16_f32 %0, %1, %2" : "=v"(r) : "v"(lo), "v"(hi));
    return r;
}

// ---------------- K1: layernorm + gate -> h_bf16 (1 wave/row, float4 loads, ushort4 stores) ----------------
__global__ __launch_bounds__(64) void k_ln(const float* __restrict__ x,
        const float* __restrict__ mask, const float* __restrict__ special,
        const float* __restrict__ lnw, const float* __restrict__ lnb,
        unsigned short* __restrict__ hb, float* __restrict__ gate) {
    int row = blockIdx.x;
    int t = threadIdx.x;
    const float4* xr = (const float4*)(x + (size_t)row * CC);
    float4 v0 = xr[t], v1 = xr[t + 64], v2 = xr[t + 128];
    float s = v0.x + v0.y + v0.z + v0.w
            + v1.x + v1.y + v1.z + v1.w
            + v2.x + v2.y + v2.z + v2.w;
    float q = v0.x * v0.x + v0.y * v0.y + v0.z * v0.z + v0.w * v0.w
            + v1.x * v1.x + v1.y * v1.y + v1.z * v1.z + v1.w * v1.w
            + v2.x * v2.x + v2.y * v2.y + v2.z * v2.z + v2.w * v2.w;
    for (int o = 32; o; o >>= 1) { s += __shfl_xor(s, o); q += __shfl_xor(q, o); }
    float mu  = s * (1.f / CC);
    float var = fmaxf(q * (1.f / CC) - mu * mu, 0.f);
    float rstd = rsqrtf(var + 1e-12f);
    const float4* lw = (const float4*)lnw;
    const float4* lb = (const float4*)lnb;
    ushort4v* hr = (ushort4v*)(hb + (size_t)row * CC);
#pragma unroll
    for (int j = 0; j < 3; ++j) {
        int i4 = t + 64 * j;
        float4 v = (j == 0) ? v0 : (j == 1) ? v1 : v2;
        float4 w = lw[i4], bso = lb[i4];
        ushort4v r;
        r[0] = f2bf((v.x - mu) * rstd * w.x + bso.x);
        r[1] = f2bf((v.y - mu) * rstd * w.y + bso.y);
        r[2] = f2bf((v.z - mu) * rstd * w.z + bso.z);
        r[3] = f2bf((v.w - mu) * rstd * w.w + bso.w);
        hr[i4] = r;
    }
    if (t == 0) gate[row] = (1.f - special[row]) * mask[row];
}

// ---------------- K2: reg_w[o][c][k] -> Wbt[kc][o][e] bf16 (coalesced both sides, 4 o/block) ----------------
__global__ __launch_bounds__(256) void k_wbt(const float* __restrict__ rw,
                                             unsigned short* __restrict__ wbt) {
    __shared__ float s[4 * GK];   // 86 KB
    int o0 = blockIdx.x * 4;
    for (int i = threadIdx.x; i < 4 * GK; i += 256)
        s[i] = rw[(size_t)(o0 + i / GK) * GK + (i % GK)];
    __syncthreads();
    for (int kc = threadIdx.x; kc < NKC; kc += 256) {
        int k = kc / 96;               // tap
        int c0 = (kc - k * 96) * 8;    // channel base
        unsigned short* dst = wbt + ((size_t)kc * CC + o0) * 8;
#pragma unroll
        for (int oo = 0; oo < 4; ++oo) {
            ushort8 r;
#pragma unroll
            for (int e = 0; e < 8; ++e) r[e] = f2bf(s[oo * GK + (c0 + e) * KHH + k]);
            *(ushort8*)(dst + oo * 8) = r;
        }
    }
}

// ---------------- K2b: conv weights -> wcb[i][c] bf16 ----------------
__global__ __launch_bounds__(256) void k_wcb(const float* __restrict__ ow, const float* __restrict__ mw,
                                             unsigned short* __restrict__ wcb) {
    int i = blockIdx.x;
    for (int c = threadIdx.x; c < CC; c += 256) {
        float v = 0.f;
        if (i < 49)      v = ow[(size_t)(i / 7) * (CC * KHH) + (size_t)c * KHH + (i % 7)];
        else if (i < 98) { int j = i - 49; v = mw[(size_t)(j / 7) * (CC * KHH) + (size_t)c * KHH + (j % 7)]; }
        wcb[(size_t)i * CC + c] = f2bf(v);
    }
}

// ---------------- K3+K4 fused: d-tile (80 rows incl. halo) in LDS -> sampling params ----------------
// 256 threads = 4 waves column-split (32 cols each); acc[5][2]; LDS: As 10KB + Bs 16KB + ds 41.6KB
__global__ __launch_bounds__(256, 2) void k_dgoff(const unsigned short* __restrict__ hb,
        const unsigned short* __restrict__ wcb,
        const float* __restrict__ offb, const float* __restrict__ modb,
        const float* __restrict__ gate,
        int* __restrict__ idx0, int* __restrict__ idx1,
        float* __restrict__ w0a, float* __restrict__ w1a) {
    __shared__ __align__(16) char As[80 * 128];
    __shared__ __align__(16) char Bs[128 * 128];
    __shared__ float ds[80][130];

    int r0 = blockIdx.x * 64;            // global row base
    int b = r0 >> 12;
    int p0 = r0 & (LL - 1);
    const unsigned short* hbB = hb + (size_t)b * LL * CC;

    int t = threadIdx.x;
    int lane = t & 63, wc = t >> 6;      // wave owns 32-col strip
    int lr = lane & 15;
    int lkb0 = (lane >> 4) * 16;

    f32x4 acc[5][2];
#pragma unroll
    for (int m = 0; m < 5; ++m)
#pragma unroll
        for (int n = 0; n < 2; ++n) acc[m][n] = (f32x4){0.f, 0.f, 0.f, 0.f};

    for (int kk = 0; kk < CC; kk += 64) {
        // stage A: 80 rows (p0-8 .. p0+71), batch-clamped to zero
#pragma unroll
        for (int s = 0; s < 3; ++s) {
            int byteoff = (s * 256 + t) * 16;
            if (byteoff < 80 * 128) {
                int row = byteoff >> 7;
                int colb = byteoff & 127;
                int pl = p0 - 8 + row;
                ushort8 v;
#pragma unroll
                for (int e = 0; e < 8; ++e) v[e] = 0;
                if (pl >= 0 && pl < LL)
                    v = *(const ushort8*)(hbB + (size_t)pl * CC + kk + (colb >> 1));
                *(ushort8*)(As + row * 128 + (colb ^ ((row & 7) << 4))) = v;
            }
        }
        // stage B: wcb rows 0..127 x 64 k
#pragma unroll
        for (int s = 0; s < 4; ++s) {
            int byteoff = (s * 256 + t) * 16;
            int row = byteoff >> 7;
            int colb = byteoff & 127;
            *(ushort8*)(Bs + row * 128 + (colb ^ ((row & 7) << 4))) =
                *(const ushort8*)(wcb + (size_t)row * CC + kk + (colb >> 1));
        }
        __syncthreads();
#pragma unroll
        for (int ks = 0; ks < 2; ++ks) {
            short8 av[5], bv[2];
            int lkb = lkb0 + ks * 64;
#pragma unroll
            for (int m = 0; m < 5; ++m) {
                int ar = m * 16 + lr;
                av[m] = *(const short8*)(As + ar * 128 + (lkb ^ ((ar & 7) << 4)));
            }
#pragma unroll
            for (int n = 0; n < 2; ++n) {
                int br = wc * 32 + n * 16 + lr;
                bv[n] = *(const short8*)(Bs + br * 128 + (lkb ^ ((br & 7) << 4)));
            }
#pragma unroll
            for (int m = 0; m < 5; ++m)
#pragma unroll
                for (int n = 0; n < 2; ++n)
                    acc[m][n] = __builtin_amdgcn_mfma_f32_16x16x32_bf16(av[m], bv[n], acc[m][n], 0, 0, 0);
        }
        __syncthreads();
    }
    // write d-tile into LDS
    int lr4 = (lane >> 4) * 4, lc = lane & 15;
#pragma unroll
    for (int m = 0; m < 5; ++m) {
#pragma unroll
        for (int n = 0; n < 2; ++n) {
            int gc = wc * 32 + n * 16 + lc;
#pragma unroll
            for (int j = 0; j < 4; ++j)
                ds[m * 16 + lr4 + j][gc] = acc[m][n][j];
        }
    }
    __syncthreads();

    // sampling params for the 64 central rows x 7 taps (448 items)
    for (int it = t; it < 64 * KHH; it += 256) {
        int pl = it / KHH;           // 0..63
        int k  = it - pl * KHH;      // 0..6
        int p  = p0 + pl;
        float offa = offb[k], moda = modb[k];
#pragma unroll
        for (int j = 0; j < KHH; ++j) {
            int qg = p + j - PADK;
            if (qg >= 0 && qg < LL) {
                offa += ds[pl + j + 5][k * 7 + j];
                moda += ds[pl + j + 5][49 + k * 7 + j];
            }
        }
        float modv = 2.f / (1.f + expf(-moda));
        float pos = (float)(p - PADK + k) + offa;
        pos = fminf(fmaxf(pos, -1.0e9f), 1.0e9f);
        float f = floorf(pos);
        float tf = pos - f;
        int i0 = (int)f;
        int i1 = i0 + 1;
        float in0 = (i0 >= 0 && i0 < LL) ? 1.f : 0.f;
        float in1 = (i1 >= 0 && i1 < LL) ? 1.f : 0.f;
        int c0 = min(max(i0, 0), LL - 1);
        int c1 = min(max(i1, 0), LL - 1);
        float g0 = gate[b * LL + c0] * in0;
        float g1 = gate[b * LL + c1] * in1;
        int flat = ((b * KHH + k) << 12) + p;
        w0a[flat] = modv * (1.f - tf) * g0;
        w1a[flat] = modv * tf * g1;
        idx0[flat] = c0;
        idx1[flat] = c1;
    }
}

// ---------------- K5: fused sample+GEMM; 8 waves x (128x48 strip), cvt_pk lerp, open scheduling ----------------
// BM=128, BN=384, BK=64; 512 threads = 8 waves (1x8), wave strip 128x48 = 8x3 frags 16x16x32

#define STEPOFF 49152   // 8 kc per step * 768 * 8 elems
#define KSOFF   24576   // 4 kc * 768 * 8 elems

#define LOADB3(Q, KS, D0, D1, D2) do { \
    const unsigned short* _q = (Q) + (KS) * KSOFF; \
    D0 = *(const short8*)(_q); \
    D1 = *(const short8*)(_q + 128); \
    D2 = *(const short8*)(_q + 256); \
} while (0)

#define MFMA_ROW3(AV, M, B0, B1, B2) \
    acc[M][0] = __builtin_amdgcn_mfma_f32_16x16x32_bf16(AV, B0, acc[M][0], 0, 0, 0); \
    acc[M][1] = __builtin_amdgcn_mfma_f32_16x16x32_bf16(AV, B1, acc[M][1], 0, 0, 0); \
    acc[M][2] = __builtin_amdgcn_mfma_f32_16x16x32_bf16(AV, B2, acc[M][2], 0, 0, 0);

#define COMPUTE_KS3(ASB, KS, B0, B1, B2) do { \
    __builtin_amdgcn_s_setprio(1); \
    int _lkb = ke0 * 2 + (KS) * 64; \
    short8 _av0, _av1, _av2, _av3, _av4, _av5, _av6, _av7; \
    { int ar = 0 * 16 + lr; _av0 = *(const short8*)((ASB) + ar * 128 + (_lkb ^ ((ar & 7) << 4))); } \
    { int ar = 1 * 16 + lr; _av1 = *(const short8*)((ASB) + ar * 128 + (_lkb ^ ((ar & 7) << 4))); } \
    { int ar = 2 * 16 + lr; _av2 = *(const short8*)((ASB) + ar * 128 + (_lkb ^ ((ar & 7) << 4))); } \
    { int ar = 3 * 16 + lr; _av3 = *(const short8*)((ASB) + ar * 128 + (_lkb ^ ((ar & 7) << 4))); } \
    MFMA_ROW3(_av0, 0, B0, B1, B2) \
    MFMA_ROW3(_av1, 1, B0, B1, B2) \
    MFMA_ROW3(_av2, 2, B0, B1, B2) \
    MFMA_ROW3(_av3, 3, B0, B1, B2) \
    { int ar = 4 * 16 + lr; _av4 = *(const short8*)((ASB) + ar * 128 + (_lkb ^ ((ar & 7) << 4))); } \
    { int ar = 5 * 16 + lr; _av5 = *(const short8*)((ASB) + ar * 128 + (_lkb ^ ((ar & 7) << 4))); } \
    { int ar = 6 * 16 + lr; _av6 = *(const short8*)((ASB) + ar * 128 + (_lkb ^ ((ar & 7) << 4))); } \
    { int ar = 7 * 16 + lr; _av7 = *(const short8*)((ASB) + ar * 128 + (_lkb ^ ((ar & 7) << 4))); } \
    MFMA_ROW3(_av4, 4, B0, B1, B2) \
    MFMA_ROW3(_av5, 5, B0, B1, B2) \
    MFMA_ROW3(_av6, 6, B0, B1, B2) \
    MFMA_ROW3(_av7, 7, B0, B1, B2) \
    __builtin_amdgcn_s_setprio(0); \
} while (0)

// counted barrier (T4): LDS drained, global loads stay in flight across the barrier
#define BAR() do { \
    asm volatile("s_waitcnt lgkmcnt(0)" ::: "memory"); \
    __builtin_amdgcn_s_barrier(); \
    __builtin_amdgcn_sched_barrier(0); \
} while (0)

__global__ __launch_bounds__(512, 2) void k_fgemm(const unsigned short* __restrict__ hb,
        const unsigned short* __restrict__ Wbt,
        const int* __restrict__ idx0, const int* __restrict__ idx1,
        const float* __restrict__ w0a, const float* __restrict__ w1a,
        const float* __restrict__ resid, float* __restrict__ out) {
    __shared__ __align__(16) char As[2][128 * 128];

    int bid = blockIdx.x;
    int nhalf = (bid & 7) >> 2;                 // XCDs 0-3 -> half 0, 4-7 -> half 1
    int rowtile = (bid >> 3) * 4 + (bid & 3);   // bijective 0..127
    int r0 = rowtile * 128;
    int o0 = nhalf * 384;
    int b = r0 >> 12;
    int p0 = r0 & (LL - 1);
    int pbase = ((b * KHH) << 12) + p0;
    const unsigned short* hbB = hb + (size_t)b * LL * CC;

    int t = threadIdx.x;
    int lane = t & 63, wc = t >> 6;             // wave 0..7 owns 48-col strip
    int lr = lane & 15;
    int ke0 = (lane >> 4) * 8;     // elem offset of lane's 8-elem k-chunk

    // per-lane B base pointer into Wbt; advances STEPOFF per step
    const unsigned short* pB = Wbt + ((size_t)(lane >> 4) * CC + o0 + wc * 48 + lr) * 8;

    // A-build mapping: row = t>>2 (0..127), seg = t&3 (16 elems each)
    int arow = t >> 2, aseg = t & 3;
    int acolb = aseg * 32;
    int aswz0 = arow * 128 + (acolb ^ ((arow & 7) << 4));
    int aswz1 = arow * 128 + ((acolb + 16) ^ ((arow & 7) << 4));

    f32x4 acc[8][3];
#pragma unroll
    for (int m = 0; m < 8; ++m)
#pragma unroll
        for (int n = 0; n < 3; ++n) acc[m][n] = (f32x4){0.f, 0.f, 0.f, 0.f};

    // per-tap sampling regs + incremental gather pointers
    float wa = 0.f, wbv = 0.f;
    int cur_tap = -1;
    const unsigned short* pA0 = hbB;
    const unsigned short* pA1 = hbB;

    // staging registers (all individually named)
    ushort8 la0, la1, la2, la3;
    short8 S0_0, S0_1, S0_2;   // ks0 buffer (even steps)
    short8 S1_0, S1_1, S1_2;   // ks1 buffer (reloaded late every step)
    short8 S2_0, S2_1, S2_2;   // ks0 buffer (odd steps)

    auto loadA = [&](int tap, int c0) {
        if (tap != cur_tap) {
            int pf = pbase + (tap << 12) + arow;
            int g0 = idx0[pf], g1 = idx1[pf];
            wa = w0a[pf];  wbv = w1a[pf];
            cur_tap = tap;
            pA0 = hbB + (size_t)g0 * CC + c0 + aseg * 16;
            pA1 = hbB + (size_t)g1 * CC + c0 + aseg * 16;
        } else {
            pA0 += 64;
            pA1 += 64;
        }
        la0 = *(const ushort8*)(pA0);
        la1 = *(const ushort8*)(pA0 + 8);
        la2 = *(const ushort8*)(pA1);
        la3 = *(const ushort8*)(pA1 + 8);
    };

    auto writeA = [&](char* Asb) {
        uint4v va, vb;
#pragma unroll
        for (int p = 0; p < 4; ++p) {
            float lo = fmaf(wa, bf2f(la0[2 * p]),     wbv * bf2f(la2[2 * p]));
            float hi = fmaf(wa, bf2f(la0[2 * p + 1]), wbv * bf2f(la2[2 * p + 1]));
            va[p] = cvtpk(lo, hi);
        }
#pragma unroll
        for (int p = 0; p < 4; ++p) {
            float lo = fmaf(wa, bf2f(la1[2 * p]),     wbv * bf2f(la3[2 * p]));
            float hi = fmaf(wa, bf2f(la1[2 * p + 1]), wbv * bf2f(la3[2 * p + 1]));
            vb[p] = cvtpk(lo, hi);
        }
        *(uint4v*)(Asb + aswz0) = va;
        *(uint4v*)(Asb + aswz1) = vb;
    };

    // prologue: step 0 fully staged
    loadA(0, 0);
    LOADB3(pB, 0, S0_0, S0_1, S0_2);
    LOADB3(pB, 1, S1_0, S1_1, S1_2);
    writeA(As[0]);
    BAR();

    int tap_c = 0, c0_c = 0;
    for (int sp = 0; sp < NT; sp += 2) {
        // ---------------- even step s = sp (computes As[0], S0/S1) ----------------
        {
            int tap_n = tap_c, c0_n = c0_c + 64;
            if (c0_n == CC) { c0_n = 0; ++tap_n; }
            bool more = (sp + 1 < NT);
            const unsigned short* pN = pB + STEPOFF;
            if (more) {
                LOADB3(pN, 0, S2_0, S2_1, S2_2);
                loadA(tap_n, c0_n);
            }
            __builtin_amdgcn_sched_barrier(0);
            COMPUTE_KS3(As[0], 0, S0_0, S0_1, S0_2);
            COMPUTE_KS3(As[0], 1, S1_0, S1_1, S1_2);
            if (more) {
                LOADB3(pN, 1, S1_0, S1_1, S1_2);
                writeA(As[1]);
            }
            BAR();
            pB = pN;
            tap_c = tap_n; c0_c = c0_n;
        }
        // ---------------- odd step s = sp+1 (computes As[1], S2/S1) ----------------
        {
            int s = sp + 1;
            if (s >= NT) break;
            int tap_n = tap_c, c0_n = c0_c + 64;
            if (c0_n == CC) { c0_n = 0; ++tap_n; }
            bool more = (s + 1 < NT);
            const unsigned short* pN = pB + STEPOFF;
            if (more) {
                LOADB3(pN, 0, S0_0, S0_1, S0_2);
                loadA(tap_n, c0_n);
            }
            __builtin_amdgcn_sched_barrier(0);
            COMPUTE_KS3(As[1], 0, S2_0, S2_1, S2_2);
            COMPUTE_KS3(As[1], 1, S1_0, S1_1, S1_2);
            if (more) {
                LOADB3(pN, 1, S1_0, S1_1, S1_2);
                writeA(As[0]);
            }
            BAR();
            pB = pN;
            tap_c = tap_n; c0_c = c0_n;
        }
    }

    // epilogue: + residual
    int lr4 = (lane >> 4) * 4, lc = lane & 15;
#pragma unroll
    for (int m = 0; m < 8; ++m) {
        int gr = r0 + m * 16 + lr4;
#pragma unroll
        for (int n = 0; n < 3; ++n) {
            int gc = o0 + wc * 48 + n * 16 + lc;
#pragma unroll
            for (int j = 0; j < 4; ++j) {
                size_t idx = (size_t)(gr + j) * CC + gc;
                out[idx] = acc[m][n][j] + resid[idx];
            }
        }
    }
}

extern "C" void kernel_launch(void* const* d_in, const int* in_sizes, int n_in,
                              void* d_out, int out_size, void* d_ws, size_t ws_size,
                              hipStream_t stream) {
    const float* x   = (const float*)d_in[0];
    const float* am  = (const float*)d_in[1];
    const float* stm = (const float*)d_in[2];
    const float* lnw = (const float*)d_in[3];
    const float* lnb = (const float*)d_in[4];
    const float* ow  = (const float*)d_in[5];
    const float* ob  = (const float*)d_in[6];
    const float* mw  = (const float*)d_in[7];
    const float* mb  = (const float*)d_in[8];
    const float* rw  = (const float*)d_in[9];
    float* out = (float*)d_out;

    char* ws = (char*)d_ws;
    size_t off = 0;
    auto carve = [&](size_t bytes) -> char* {
        char* p = ws + off;
        off += (bytes + 255) & ~(size_t)255;
        return p;
    };
    unsigned short* hb  = (unsigned short*)carve((size_t)ROWS * CC * 2);   // 25.2 MB
    unsigned short* wbt = (unsigned short*)carve((size_t)NKC * CC * 8 * 2);// 8.25 MB
    unsigned short* wcb = (unsigned short*)carve((size_t)128 * CC * 2);    // 0.20 MB
    float* gate = (float*)carve((size_t)ROWS * 4);
    int*   i0   = (int*)carve((size_t)NKP * 4);
    int*   i1   = (int*)carve((size_t)NKP * 4);
    float* w0   = (float*)carve((size_t)NKP * 4);
    float* w1   = (float*)carve((size_t)NKP * 4);

    k_ln<<<ROWS, 64, 0, stream>>>(x, am, stm, lnw, lnb, hb, gate);
    k_wbt<<<CC / 4, 256, 0, stream>>>(rw, wbt);
    k_wcb<<<128, 256, 0, stream>>>(ow, mw, wcb);
    k_dgoff<<<ROWS / 64, 256, 0, stream>>>(hb, wcb, ob, mb, gate, i0, i1, w0, w1);
    k_fgemm<<<256, 512, 0, stream>>>(hb, wbt, i0, i1, w0, w1, x, out);
}

// Round 18
// 175.905 us; speedup vs baseline: 1.0661x; 1.0661x over previous
//
#include <hip/hip_runtime.h>
#include <math.h>

#define BB 4
#define LL 4096
#define CC 768
#define KHH 7
#define PADK 3
#define ROWS (BB*LL)      // 16384
#define NKP  (BB*KHH*LL)  // 114688
#define GK   (KHH*CC)     // 5376
#define NT   (GK/64)      // 84
#define NKC  (GK/8)       // 672

// k_prep block-range dispatch
#define NB_LN   (ROWS/4)          // 4096 blocks, 4 rows each (1/wave)
#define NB_WBT  CC                // 768 blocks, one o each
#define NB_WCB  128               // 128 blocks, one i each
#define NB_PREP (NB_LN + NB_WBT + NB_WCB)

typedef unsigned short ushort8 __attribute__((ext_vector_type(8)));
typedef unsigned short ushort4v __attribute__((ext_vector_type(4)));
typedef short short8 __attribute__((ext_vector_type(8)));
typedef float f32x4 __attribute__((ext_vector_type(4)));
typedef unsigned int uint4v __attribute__((ext_vector_type(4)));

__device__ __forceinline__ float bf2f(unsigned short u) {
    return __uint_as_float(((unsigned)u) << 16);
}
__device__ __forceinline__ unsigned short f2bf(float x) {
    unsigned u = __float_as_uint(x);
    return (unsigned short)((u + 0x7FFFu + ((u >> 16) & 1u)) >> 16);
}
__device__ __forceinline__ unsigned cvtpk(float lo, float hi) {
    unsigned r;
    asm("v_cvt_pk_bf16_f32 %0, %1, %2" : "=v"(r) : "v"(lo), "v"(hi));
    return r;
}

// ---------------- K1 merged prep: LN (blocks 0..4095) | Wbt (4096..4863) | wcb (4864..4991) ----------------
__global__ __launch_bounds__(256) void k_prep(const float* __restrict__ x,
        const float* __restrict__ mask, const float* __restrict__ special,
        const float* __restrict__ lnw, const float* __restrict__ lnb,
        const float* __restrict__ rw,
        const float* __restrict__ ow, const float* __restrict__ mw,
        unsigned short* __restrict__ hb, float* __restrict__ gate,
        unsigned short* __restrict__ wbt, unsigned short* __restrict__ wcb) {
    __shared__ float s[GK];   // 21.5 KB (wbt part only)
    int bid = blockIdx.x;
    int t = threadIdx.x;

    if (bid < NB_LN) {
        // ---- layernorm: one row per wave ----
        int row = bid * 4 + (t >> 6);
        int lane = t & 63;
        const float4* xr = (const float4*)(x + (size_t)row * CC);
        float4 v0 = xr[lane], v1 = xr[lane + 64], v2 = xr[lane + 128];
        float sacc = v0.x + v0.y + v0.z + v0.w
                   + v1.x + v1.y + v1.z + v1.w
                   + v2.x + v2.y + v2.z + v2.w;
        float q = v0.x * v0.x + v0.y * v0.y + v0.z * v0.z + v0.w * v0.w
                + v1.x * v1.x + v1.y * v1.y + v1.z * v1.z + v1.w * v1.w
                + v2.x * v2.x + v2.y * v2.y + v2.z * v2.z + v2.w * v2.w;
        for (int o = 32; o; o >>= 1) { sacc += __shfl_xor(sacc, o); q += __shfl_xor(q, o); }
        float mu  = sacc * (1.f / CC);
        float var = fmaxf(q * (1.f / CC) - mu * mu, 0.f);
        float rstd = rsqrtf(var + 1e-12f);
        const float4* lw = (const float4*)lnw;
        const float4* lb = (const float4*)lnb;
        ushort4v* hr = (ushort4v*)(hb + (size_t)row * CC);
#pragma unroll
        for (int j = 0; j < 3; ++j) {
            int i4 = lane + 64 * j;
            float4 v = (j == 0) ? v0 : (j == 1) ? v1 : v2;
            float4 w = lw[i4], bso = lb[i4];
            ushort4v r;
            r[0] = f2bf((v.x - mu) * rstd * w.x + bso.x);
            r[1] = f2bf((v.y - mu) * rstd * w.y + bso.y);
            r[2] = f2bf((v.z - mu) * rstd * w.z + bso.z);
            r[3] = f2bf((v.w - mu) * rstd * w.w + bso.w);
            hr[i4] = r;
        }
        if (lane == 0) gate[row] = (1.f - special[row]) * mask[row];
    } else if (bid < NB_LN + NB_WBT) {
        // ---- reg_w[o][c][k] -> Wbt[kc][o][e] bf16, one o per block ----
        int o = bid - NB_LN;
        for (int i = t; i < GK; i += 256) s[i] = rw[(size_t)o * GK + i];
        __syncthreads();
        unsigned short* orow = wbt;
        for (int kc = t; kc < NKC; kc += 256) {
            int k = kc / 96;
            int c0 = (kc - k * 96) * 8;
            ushort8 r;
#pragma unroll
            for (int e = 0; e < 8; ++e) r[e] = f2bf(s[(c0 + e) * KHH + k]);
            *(ushort8*)(orow + ((size_t)kc * CC + o) * 8) = r;
        }
    } else {
        // ---- conv weights -> wcb[i][c] bf16, one i per block ----
        int i = bid - NB_LN - NB_WBT;
        for (int c = t; c < CC; c += 256) {
            float v = 0.f;
            if (i < 49)      v = ow[(size_t)(i / 7) * (CC * KHH) + (size_t)c * KHH + (i % 7)];
            else if (i < 98) { int j = i - 49; v = mw[(size_t)(j / 7) * (CC * KHH) + (size_t)c * KHH + (j % 7)]; }
            wcb[(size_t)i * CC + c] = f2bf(v);
        }
    }
}

// ---------------- K3: d[row][i] = sum_c hb[row][c] * wcb[i][c]  (BM=64 -> 256 blocks) ----------------
__global__ __launch_bounds__(256) void k_dg2(const unsigned short* __restrict__ A,
        const unsigned short* __restrict__ Bm, float* __restrict__ d) {
    __shared__ __align__(16) char As[64 * 128];
    __shared__ __align__(16) char Bs[128 * 128];
    int r0 = blockIdx.x * 64;
    int t = threadIdx.x;
    int lane = t & 63, w = t >> 6;
    int wr = w >> 1, wc = w & 1;
    f32x4 acc[2][4];
#pragma unroll
    for (int m = 0; m < 2; ++m)
#pragma unroll
        for (int n = 0; n < 4; ++n) acc[m][n] = (f32x4){0.f, 0.f, 0.f, 0.f};
    int lr = lane & 15;
    int lkb0 = (lane >> 4) * 16;
    for (int kk = 0; kk < CC; kk += 64) {
#pragma unroll
        for (int s = 0; s < 2; ++s) {
            int byteoff = (s * 256 + t) * 16;
            int row = byteoff >> 7;
            int colb = byteoff & 127;
            int sw = (row * 128 + colb) ^ ((row & 7) << 4);
            *(ushort8*)(As + sw) = *(const ushort8*)(A + (size_t)(r0 + row) * CC + kk + (colb >> 1));
        }
#pragma unroll
        for (int s = 0; s < 4; ++s) {
            int byteoff = (s * 256 + t) * 16;
            int row = byteoff >> 7;
            int colb = byteoff & 127;
            int sw = (row * 128 + colb) ^ ((row & 7) << 4);
            *(ushort8*)(Bs + sw) = *(const ushort8*)(Bm + (size_t)row * CC + kk + (colb >> 1));
        }
        __syncthreads();
#pragma unroll
        for (int ks = 0; ks < 2; ++ks) {
            short8 av[2], bv[4];
            int lkb = lkb0 + ks * 64;
#pragma unroll
            for (int m = 0; m < 2; ++m) {
                int ar = wr * 32 + m * 16 + lr;
                av[m] = *(const short8*)(As + ((ar * 128 + lkb) ^ ((ar & 7) << 4)));
            }
#pragma unroll
            for (int n = 0; n < 4; ++n) {
                int br = wc * 64 + n * 16 + lr;
                bv[n] = *(const short8*)(Bs + ((br * 128 + lkb) ^ ((br & 7) << 4)));
            }
#pragma unroll
            for (int m = 0; m < 2; ++m)
#pragma unroll
                for (int n = 0; n < 4; ++n)
                    acc[m][n] = __builtin_amdgcn_mfma_f32_16x16x32_bf16(av[m], bv[n], acc[m][n], 0, 0, 0);
        }
        __syncthreads();
    }
    int lr4 = (lane >> 4) * 4, lc = lane & 15;
#pragma unroll
    for (int m = 0; m < 2; ++m) {
        int gr = r0 + wr * 32 + m * 16 + lr4;
#pragma unroll
        for (int n = 0; n < 4; ++n) {
            int gc = wc * 64 + n * 16 + lc;
#pragma unroll
            for (int j = 0; j < 4; ++j)
                d[(size_t)(gr + j) * 128 + gc] = acc[m][n][j];
        }
    }
}

// ---------------- K4: sampling params ----------------
__global__ __launch_bounds__(256) void k_off(const float* __restrict__ d,
        const float* __restrict__ offb, const float* __restrict__ modb,
        const float* __restrict__ gate,
        int* __restrict__ idx0, int* __restrict__ idx1,
        float* __restrict__ w0a, float* __restrict__ w1a) {
    int flat = blockIdx.x * 256 + threadIdx.x;   // b*7*L + k*L + p
    if (flat >= NKP) return;
    int p = flat & (LL - 1);
    int k = (flat >> 12) % KHH;
    int b = flat / (KHH * LL);
    float offa = offb[k], moda = modb[k];
#pragma unroll
    for (int j = 0; j < KHH; ++j) {
        int q = p + j - PADK;
        if (q >= 0 && q < LL) {
            const float* dr = d + (size_t)(b * LL + q) * 128;
            offa += dr[k * 7 + j];
            moda += dr[49 + k * 7 + j];
        }
    }
    float modv = 2.f / (1.f + expf(-moda));
    float pos = (float)(p - PADK + k) + offa;
    pos = fminf(fmaxf(pos, -1.0e9f), 1.0e9f);
    float f = floorf(pos);
    float tf = pos - f;
    int i0 = (int)f;
    int i1 = i0 + 1;
    float in0 = (i0 >= 0 && i0 < LL) ? 1.f : 0.f;
    float in1 = (i1 >= 0 && i1 < LL) ? 1.f : 0.f;
    int c0 = min(max(i0, 0), LL - 1);
    int c1 = min(max(i1, 0), LL - 1);
    float g0 = gate[b * LL + c0] * in0;
    float g1 = gate[b * LL + c1] * in1;
    w0a[flat] = modv * (1.f - tf) * g0;
    w1a[flat] = modv * tf * g1;
    idx0[flat] = c0;
    idx1[flat] = c1;
}

// ---------------- K5: fused sample+GEMM; 8 waves x (128x48 strip), cvt_pk lerp, open scheduling ----------------
// BM=128, BN=384, BK=64; 512 threads = 8 waves (1x8), wave strip 128x48 = 8x3 frags 16x16x32

#define STEPOFF 49152   // 8 kc per step * 768 * 8 elems
#define KSOFF   24576   // 4 kc * 768 * 8 elems

#define LOADB3(Q, KS, D0, D1, D2) do { \
    const unsigned short* _q = (Q) + (KS) * KSOFF; \
    D0 = *(const short8*)(_q); \
    D1 = *(const short8*)(_q + 128); \
    D2 = *(const short8*)(_q + 256); \
} while (0)

#define MFMA_ROW3(AV, M, B0, B1, B2) \
    acc[M][0] = __builtin_amdgcn_mfma_f32_16x16x32_bf16(AV, B0, acc[M][0], 0, 0, 0); \
    acc[M][1] = __builtin_amdgcn_mfma_f32_16x16x32_bf16(AV, B1, acc[M][1], 0, 0, 0); \
    acc[M][2] = __builtin_amdgcn_mfma_f32_16x16x32_bf16(AV, B2, acc[M][2], 0, 0, 0);

#define COMPUTE_KS3(ASB, KS, B0, B1, B2) do { \
    __builtin_amdgcn_s_setprio(1); \
    int _lkb = ke0 * 2 + (KS) * 64; \
    short8 _av0, _av1, _av2, _av3, _av4, _av5, _av6, _av7; \
    { int ar = 0 * 16 + lr; _av0 = *(const short8*)((ASB) + ar * 128 + (_lkb ^ ((ar & 7) << 4))); } \
    { int ar = 1 * 16 + lr; _av1 = *(const short8*)((ASB) + ar * 128 + (_lkb ^ ((ar & 7) << 4))); } \
    { int ar = 2 * 16 + lr; _av2 = *(const short8*)((ASB) + ar * 128 + (_lkb ^ ((ar & 7) << 4))); } \
    { int ar = 3 * 16 + lr; _av3 = *(const short8*)((ASB) + ar * 128 + (_lkb ^ ((ar & 7) << 4))); } \
    MFMA_ROW3(_av0, 0, B0, B1, B2) \
    MFMA_ROW3(_av1, 1, B0, B1, B2) \
    MFMA_ROW3(_av2, 2, B0, B1, B2) \
    MFMA_ROW3(_av3, 3, B0, B1, B2) \
    { int ar = 4 * 16 + lr; _av4 = *(const short8*)((ASB) + ar * 128 + (_lkb ^ ((ar & 7) << 4))); } \
    { int ar = 5 * 16 + lr; _av5 = *(const short8*)((ASB) + ar * 128 + (_lkb ^ ((ar & 7) << 4))); } \
    { int ar = 6 * 16 + lr; _av6 = *(const short8*)((ASB) + ar * 128 + (_lkb ^ ((ar & 7) << 4))); } \
    { int ar = 7 * 16 + lr; _av7 = *(const short8*)((ASB) + ar * 128 + (_lkb ^ ((ar & 7) << 4))); } \
    MFMA_ROW3(_av4, 4, B0, B1, B2) \
    MFMA_ROW3(_av5, 5, B0, B1, B2) \
    MFMA_ROW3(_av6, 6, B0, B1, B2) \
    MFMA_ROW3(_av7, 7, B0, B1, B2) \
    __builtin_amdgcn_s_setprio(0); \
} while (0)

// counted barrier (T4): LDS drained, global loads stay in flight across the barrier
#define BAR() do { \
    asm volatile("s_waitcnt lgkmcnt(0)" ::: "memory"); \
    __builtin_amdgcn_s_barrier(); \
    __builtin_amdgcn_sched_barrier(0); \
} while (0)

__global__ __launch_bounds__(512, 2) void k_fgemm(const unsigned short* __restrict__ hb,
        const unsigned short* __restrict__ Wbt,
        const int* __restrict__ idx0, const int* __restrict__ idx1,
        const float* __restrict__ w0a, const float* __restrict__ w1a,
        const float* __restrict__ resid, float* __restrict__ out) {
    __shared__ __align__(16) char As[2][128 * 128];

    int bid = blockIdx.x;
    int nhalf = (bid & 7) >> 2;                 // XCDs 0-3 -> half 0, 4-7 -> half 1
    int rowtile = (bid >> 3) * 4 + (bid & 3);   // bijective 0..127
    int r0 = rowtile * 128;
    int o0 = nhalf * 384;
    int b = r0 >> 12;
    int p0 = r0 & (LL - 1);
    int pbase = ((b * KHH) << 12) + p0;
    const unsigned short* hbB = hb + (size_t)b * LL * CC;

    int t = threadIdx.x;
    int lane = t & 63, wc = t >> 6;             // wave 0..7 owns 48-col strip
    int lr = lane & 15;
    int ke0 = (lane >> 4) * 8;     // elem offset of lane's 8-elem k-chunk

    // per-lane B base pointer into Wbt; advances STEPOFF per step
    const unsigned short* pB = Wbt + ((size_t)(lane >> 4) * CC + o0 + wc * 48 + lr) * 8;

    // A-build mapping: row = t>>2 (0..127), seg = t&3 (16 elems each)
    int arow = t >> 2, aseg = t & 3;
    int acolb = aseg * 32;
    int aswz0 = arow * 128 + (acolb ^ ((arow & 7) << 4));
    int aswz1 = arow * 128 + ((acolb + 16) ^ ((arow & 7) << 4));

    f32x4 acc[8][3];
#pragma unroll
    for (int m = 0; m < 8; ++m)
#pragma unroll
        for (int n = 0; n < 3; ++n) acc[m][n] = (f32x4){0.f, 0.f, 0.f, 0.f};

    // per-tap sampling regs + incremental gather pointers
    float wa = 0.f, wbv = 0.f;
    int cur_tap = -1;
    const unsigned short* pA0 = hbB;
    const unsigned short* pA1 = hbB;

    // staging registers (all individually named)
    ushort8 la0, la1, la2, la3;
    short8 S0_0, S0_1, S0_2;   // ks0 buffer (even steps)
    short8 S1_0, S1_1, S1_2;   // ks1 buffer (reloaded late every step)
    short8 S2_0, S2_1, S2_2;   // ks0 buffer (odd steps)

    auto loadA = [&](int tap, int c0) {
        if (tap != cur_tap) {
            int pf = pbase + (tap << 12) + arow;
            int g0 = idx0[pf], g1 = idx1[pf];
            wa = w0a[pf];  wbv = w1a[pf];
            cur_tap = tap;
            pA0 = hbB + (size_t)g0 * CC + c0 + aseg * 16;
            pA1 = hbB + (size_t)g1 * CC + c0 + aseg * 16;
        } else {
            pA0 += 64;
            pA1 += 64;
        }
        la0 = *(const ushort8*)(pA0);
        la1 = *(const ushort8*)(pA0 + 8);
        la2 = *(const ushort8*)(pA1);
        la3 = *(const ushort8*)(pA1 + 8);
    };

    auto writeA = [&](char* Asb) {
        uint4v va, vb;
#pragma unroll
        for (int p = 0; p < 4; ++p) {
            float lo = fmaf(wa, bf2f(la0[2 * p]),     wbv * bf2f(la2[2 * p]));
            float hi = fmaf(wa, bf2f(la0[2 * p + 1]), wbv * bf2f(la2[2 * p + 1]));
            va[p] = cvtpk(lo, hi);
        }
#pragma unroll
        for (int p = 0; p < 4; ++p) {
            float lo = fmaf(wa, bf2f(la1[2 * p]),     wbv * bf2f(la3[2 * p]));
            float hi = fmaf(wa, bf2f(la1[2 * p + 1]), wbv * bf2f(la3[2 * p + 1]));
            vb[p] = cvtpk(lo, hi);
        }
        *(uint4v*)(Asb + aswz0) = va;
        *(uint4v*)(Asb + aswz1) = vb;
    };

    // prologue: step 0 fully staged
    loadA(0, 0);
    LOADB3(pB, 0, S0_0, S0_1, S0_2);
    LOADB3(pB, 1, S1_0, S1_1, S1_2);
    writeA(As[0]);
    BAR();

    int tap_c = 0, c0_c = 0;
    for (int sp = 0; sp < NT; sp += 2) {
        // ---------------- even step s = sp (computes As[0], S0/S1) ----------------
        {
            int tap_n = tap_c, c0_n = c0_c + 64;
            if (c0_n == CC) { c0_n = 0; ++tap_n; }
            bool more = (sp + 1 < NT);
            const unsigned short* pN = pB + STEPOFF;
            if (more) {
                LOADB3(pN, 0, S2_0, S2_1, S2_2);
                loadA(tap_n, c0_n);
            }
            __builtin_amdgcn_sched_barrier(0);
            COMPUTE_KS3(As[0], 0, S0_0, S0_1, S0_2);
            COMPUTE_KS3(As[0], 1, S1_0, S1_1, S1_2);
            if (more) {
                LOADB3(pN, 1, S1_0, S1_1, S1_2);
                writeA(As[1]);
            }
            BAR();
            pB = pN;
            tap_c = tap_n; c0_c = c0_n;
        }
        // ---------------- odd step s = sp+1 (computes As[1], S2/S1) ----------------
        {
            int s = sp + 1;
            if (s >= NT) break;
            int tap_n = tap_c, c0_n = c0_c + 64;
            if (c0_n == CC) { c0_n = 0; ++tap_n; }
            bool more = (s + 1 < NT);
            const unsigned short* pN = pB + STEPOFF;
            if (more) {
                LOADB3(pN, 0, S0_0, S0_1, S0_2);
                loadA(tap_n, c0_n);
            }
            __builtin_amdgcn_sched_barrier(0);
            COMPUTE_KS3(As[1], 0, S2_0, S2_1, S2_2);
            COMPUTE_KS3(As[1], 1, S1_0, S1_1, S1_2);
            if (more) {
                LOADB3(pN, 1, S1_0, S1_1, S1_2);
                writeA(As[0]);
            }
            BAR();
            pB = pN;
            tap_c = tap_n; c0_c = c0_n;
        }
    }

    // epilogue: + residual
    int lr4 = (lane >> 4) * 4, lc = lane & 15;
#pragma unroll
    for (int m = 0; m < 8; ++m) {
        int gr = r0 + m * 16 + lr4;
#pragma unroll
        for (int n = 0; n < 3; ++n) {
            int gc = o0 + wc * 48 + n * 16 + lc;
#pragma unroll
            for (int j = 0; j < 4; ++j) {
                size_t idx = (size_t)(gr + j) * CC + gc;
                out[idx] = acc[m][n][j] + resid[idx];
            }
        }
    }
}

extern "C" void kernel_launch(void* const* d_in, const int* in_sizes, int n_in,
                              void* d_out, int out_size, void* d_ws, size_t ws_size,
                              hipStream_t stream) {
    const float* x   = (const float*)d_in[0];
    const float* am  = (const float*)d_in[1];
    const float* stm = (const float*)d_in[2];
    const float* lnw = (const float*)d_in[3];
    const float* lnb = (const float*)d_in[4];
    const float* ow  = (const float*)d_in[5];
    const float* ob  = (const float*)d_in[6];
    const float* mw  = (const float*)d_in[7];
    const float* mb  = (const float*)d_in[8];
    const float* rw  = (const float*)d_in[9];
    float* out = (float*)d_out;

    char* ws = (char*)d_ws;
    size_t off = 0;
    auto carve = [&](size_t bytes) -> char* {
        char* p = ws + off;
        off += (bytes + 255) & ~(size_t)255;
        return p;
    };
    unsigned short* hb  = (unsigned short*)carve((size_t)ROWS * CC * 2);   // 25.2 MB
    unsigned short* wbt = (unsigned short*)carve((size_t)NKC * CC * 8 * 2);// 8.25 MB
    unsigned short* wcb = (unsigned short*)carve((size_t)128 * CC * 2);    // 0.20 MB
    float* d    = (float*)carve((size_t)ROWS * 128 * 4);                   // 8.4 MB
    float* gate = (float*)carve((size_t)ROWS * 4);
    int*   i0   = (int*)carve((size_t)NKP * 4);
    int*   i1   = (int*)carve((size_t)NKP * 4);
    float* w0   = (float*)carve((size_t)NKP * 4);
    float* w1   = (float*)carve((size_t)NKP * 4);

    k_prep<<<NB_PREP, 256, 0, stream>>>(x, am, stm, lnw, lnb, rw, ow, mw, hb, gate, wbt, wcb);
    k_dg2<<<ROWS / 64, 256, 0, stream>>>(hb, wcb, d);
    k_off<<<NKP / 256, 256, 0, stream>>>(d, ob, mb, gate, i0, i1, w0, w1);
    k_fgemm<<<256, 512, 0, stream>>>(hb, wbt, i0, i1, w0, w1, x, out);
}